// Round 11
// baseline (950.083 us; speedup 1.0000x reference)
//
#include <hip/hip_runtime.h>
#include <hip/hip_bf16.h>
#include <stdint.h>

typedef __hip_bfloat16 bf16;
typedef short bf16x8 __attribute__((ext_vector_type(8)));
typedef float f32x4 __attribute__((ext_vector_type(4)));

#define MFMA16(a, b, c) __builtin_amdgcn_mfma_f32_16x16x32_bf16((a), (b), (c), 0, 0, 0)

__device__ __forceinline__ void gload16(const void* g, void* l) {
  __builtin_amdgcn_global_load_lds((const __attribute__((address_space(1))) void*)g,
                                   (__attribute__((address_space(3))) void*)l,
                                   16, 0, 0);
}

__device__ __forceinline__ void stv(float* p, float v) { *p = v; }
__device__ __forceinline__ void stv(bf16* p, float v) { *p = __float2bfloat16(v); }

// ---------------------------------------------------------------------------
// fp32 -> bf16 cast (vectorized, grid-stride). n % 8 == 0.
// ---------------------------------------------------------------------------
__global__ void cast_f32_bf16(const float* __restrict__ in, bf16* __restrict__ out,
                              long n) {
  const long stride = (long)gridDim.x * blockDim.x * 8;
  for (long i = ((long)blockIdx.x * blockDim.x + threadIdx.x) * 8; i < n; i += stride) {
    const float4 a = *(const float4*)&in[i];
    const float4 b = *(const float4*)&in[i + 4];
    bf16 t[8];
    t[0] = __float2bfloat16(a.x); t[1] = __float2bfloat16(a.y);
    t[2] = __float2bfloat16(a.z); t[3] = __float2bfloat16(a.w);
    t[4] = __float2bfloat16(b.x); t[5] = __float2bfloat16(b.y);
    t[6] = __float2bfloat16(b.z); t[7] = __float2bfloat16(b.w);
    *(bf16x8*)&out[i] = *(const bf16x8*)t;
  }
}

// ---------------------------------------------------------------------------
// GEMM (r9-verified): C[M,N] = A[M,K] * B[N,K]^T.  256x256 tile, BK=32,
// 8 waves, 4-deep ring, counted vmcnt(8), 2-phase K-step.
// ---------------------------------------------------------------------------
template <typename OutT>
__global__ __launch_bounds__(512, 2) void gemm256(const bf16* __restrict__ A,
                                                  const bf16* __restrict__ B,
                                                  OutT* __restrict__ C,
                                                  int M, int N, int K) {
  const int nbn = N >> 8;
  const int nwg = gridDim.x;
  const int wg = blockIdx.x;
  const int cpx = nwg >> 3;                    // nwg % 8 == 0 guaranteed
  const int swz = (wg & 7) * cpx + (wg >> 3);  // XCD-aware swizzle (bijective)
  const int bm = swz / nbn;
  const int bn = swz - bm * nbn;

  __shared__ bf16 As[4][256][32];  // 64 KB ring
  __shared__ bf16 Bs[4][256][32];  // 64 KB ring

  const int tid = threadIdx.x;
  const int wave = tid >> 6, lane = tid & 63;
  const int lo = lane & 15, hi = lane >> 4;
  const int wm = wave >> 2, wn = wave & 3;

  const bf16* Ag = A + (long)(bm * 256) * K;
  const bf16* Bg = B + (long)(bn * 256) * K;

  int srow[2], scol[2];
#pragma unroll
  for (int j = 0; j < 2; j++) {
    const int c = wave * 128 + j * 64 + lane;
    const int row = c >> 2, cc = c & 3;
    const int ccl = cc ^ ((row >> 2) & 1) ^ (((row >> 3) & 1) << 1);  // inverse swz
    srow[j] = row;
    scol[j] = ccl * 8;
  }

  const int rsw = ((lo >> 2) & 1) ^ (((lo >> 3) & 1) << 1);
  const int colb = (hi ^ rsw) * 8;

  f32x4 acc[8][4] = {};
  const int NT = K >> 5;

#pragma unroll
  for (int p = 0; p < 3; p++) {
#pragma unroll
    for (int j = 0; j < 2; j++)
      gload16(Ag + (long)srow[j] * K + p * 32 + scol[j], &As[p][wave * 32 + j * 16][0]);
#pragma unroll
    for (int j = 0; j < 2; j++)
      gload16(Bg + (long)srow[j] * K + p * 32 + scol[j], &Bs[p][wave * 32 + j * 16][0]);
  }

#pragma unroll 1
  for (int t = 0; t < NT; ++t) {
    const int ahead = NT - 1 - t;
    if (ahead >= 2)      asm volatile("s_waitcnt vmcnt(8)" ::: "memory");
    else if (ahead == 1) asm volatile("s_waitcnt vmcnt(4)" ::: "memory");
    else                 asm volatile("s_waitcnt vmcnt(0)" ::: "memory");
    __builtin_amdgcn_s_barrier();

    const bf16(*Ab)[32] = As[t & 3];
    const bf16(*Bb)[32] = Bs[t & 3];
    const bool st = (t + 3 < NT);
    const int kt = (t + 3) * 32;
    const int s = (t + 3) & 3;

    bf16x8 af[8], bfr[4];
    // ---- phase 1: A-frags + bf01 reads, stage A(t+3), barrier, 16 MFMA ----
#pragma unroll
    for (int m = 0; m < 8; m++)
      af[m] = *(const bf16x8*)&Ab[wm * 128 + m * 16 + lo][colb];
#pragma unroll
    for (int n = 0; n < 2; n++)
      bfr[n] = *(const bf16x8*)&Bb[wn * 64 + n * 16 + lo][colb];
    if (st) {
#pragma unroll
      for (int j = 0; j < 2; j++)
        gload16(Ag + (long)srow[j] * K + kt + scol[j], &As[s][wave * 32 + j * 16][0]);
    }
    __builtin_amdgcn_s_barrier();
    __builtin_amdgcn_s_setprio(1);
#pragma unroll
    for (int m = 0; m < 8; m++)
#pragma unroll
      for (int n = 0; n < 2; n++) acc[m][n] = MFMA16(af[m], bfr[n], acc[m][n]);
    __builtin_amdgcn_s_setprio(0);
    __builtin_amdgcn_s_barrier();

    // ---- phase 2: bf23 reads, stage B(t+3), barrier, 16 MFMA ----
#pragma unroll
    for (int n = 2; n < 4; n++)
      bfr[n] = *(const bf16x8*)&Bb[wn * 64 + n * 16 + lo][colb];
    if (st) {
#pragma unroll
      for (int j = 0; j < 2; j++)
        gload16(Bg + (long)srow[j] * K + kt + scol[j], &Bs[s][wave * 32 + j * 16][0]);
    }
    __builtin_amdgcn_s_barrier();
    __builtin_amdgcn_s_setprio(1);
#pragma unroll
    for (int m = 0; m < 8; m++)
#pragma unroll
      for (int n = 2; n < 4; n++) acc[m][n] = MFMA16(af[m], bfr[n], acc[m][n]);
    __builtin_amdgcn_s_setprio(0);
  }

  const long crow0 = (long)bm * 256 + wm * 128;
  const long ccol0 = (long)bn * 256 + wn * 64;
#pragma unroll
  for (int m = 0; m < 8; m++)
#pragma unroll
    for (int n = 0; n < 4; n++)
#pragma unroll
      for (int r = 0; r < 4; r++)
        stv(&C[(crow0 + m * 16 + hi * 4 + r) * (long)N + ccol0 + n * 16 + lo],
            acc[m][n][r]);
}

// ---------------------------------------------------------------------------
// RoPE in-place on qkv[4096][6144]; Q slots also scaled by 1/sqrt(128).
// ---------------------------------------------------------------------------
__global__ void rope_qk(bf16* __restrict__ qkv) {
  const int row = blockIdx.x;
  const int t = row & 2047;
  const float scale = 0.08838834764831845f;  // 128^-0.5
  for (int p = threadIdx.x; p < 40 * 64; p += blockDim.x) {
    const int sh = p >> 6, j = p & 63;
    const int kvh = sh / 5, slot = sh - kvh * 5;
    const long base = (long)row * 6144 + kvh * 768 + slot * 128 + j;
    const float x1 = __bfloat162float(qkv[base]);
    const float x2 = __bfloat162float(qkv[base + 64]);
    const float inv = __expf(-(float)j * 0.14391156831212787f);  // ln(1e4)/64
    const float ang = (float)t * inv;
    const float c = cosf(ang), s = sinf(ang);
    float o1 = x1 * c - x2 * s;
    float o2 = x2 * c + x1 * s;
    if (slot < 4) { o1 *= scale; o2 *= scale; }
    qkv[base] = __float2bfloat16(o1);
    qkv[base + 64] = __float2bfloat16(o2);
  }
}

// ---------------------------------------------------------------------------
// V transpose: qkv V-slice [t][d] -> Vt[b][kvh][d][t]  (64x64 tiles via LDS)
// ---------------------------------------------------------------------------
__global__ void vtrans(const bf16* __restrict__ qkv, bf16* __restrict__ Vt) {
  const int tt = blockIdx.x, dd = blockIdx.y, bk = blockIdx.z;
  const int kvh = bk & 7, b = bk >> 3;
  __shared__ bf16 tile[64][65];
  const int tx = threadIdx.x, ty = threadIdx.y;
  const bf16* src = qkv + ((long)(b * 2048 + tt * 64)) * 6144 + kvh * 768 + 640 + dd * 64;
  for (int r = ty; r < 64; r += 4) tile[r][tx] = src[(long)r * 6144 + tx];
  __syncthreads();
  bf16* dst = Vt + ((long)bk * 128 + dd * 64) * 2048 + tt * 64;
  for (int r = ty; r < 64; r += 4) dst[(long)r * 2048 + tx] = tile[tx][r];
}

// ---------------------------------------------------------------------------
// Causal GQA flash attention, KV-SPLIT variant (round 11).
// r9 per-wave inner loop kept EXACTLY (KVBLK=32, 128 VGPR); each block
// covers HALF the kt-range (hf) of its two paired q-tiles (z, 63-z) ->
// 1024 blocks x 4 waves = 4096 uniform waves (33/32 iters). Partials:
// Pacc bf16 [hf][b][h][2048][128], Pml f32 [hf][b][h][2048][2] (m, l).
// grid 1024, block 256.
// ---------------------------------------------------------------------------
__global__ __launch_bounds__(256) void attn_split(const bf16* __restrict__ qkv,
                                                  const bf16* __restrict__ Vt,
                                                  bf16* __restrict__ Pacc,
                                                  float* __restrict__ Pml) {
  const int lin = blockIdx.x;                  // 0..1023
  const int c = (lin & 7) * 128 + (lin >> 3);  // XCD-contiguous chunks of 128
  const int z = c & 31;
  const int hf = (c >> 5) & 1;
  const int kvh = (c >> 6) & 7;
  const int b = c >> 9;

  const int wave = threadIdx.x >> 6;
  const int lane = threadIdx.x & 63;
  const int h = kvh * 4 + wave;
  const int lo = lane & 15, hi = lane >> 4;

  const bf16* Qb = qkv + (long)b * 2048 * 6144 + kvh * 768 + wave * 128;
  const bf16* Kb = qkv + (long)b * 2048 * 6144 + kvh * 768 + 512;
  const bf16* Vb = Vt + ((long)(b * 8 + kvh)) * 128 * 2048;

  __shared__ bf16 Plds[4][32][40];  // per-wave, padded rows

  const long hoff = (long)hf * 131072;  // rows per half

#pragma unroll 1
  for (int pass = 0; pass < 2; ++pass) {
    const int qw = pass ? 63 - z : z;
    const int q0 = qw * 32;
    const int L = qw + 1;
    const int ktA = hf ? ((L + 1) >> 1) : 0;
    const int ktB = hf ? L : ((L + 1) >> 1);

    bf16x8 qf[2][4];
#pragma unroll
    for (int qb = 0; qb < 2; qb++)
#pragma unroll
      for (int dc = 0; dc < 4; dc++)
        qf[qb][dc] =
            *(const bf16x8*)&Qb[(long)(q0 + qb * 16 + lo) * 6144 + dc * 32 + hi * 8];

    f32x4 acc[2][8] = {};
    float mrow[2][4], lrow[2][4];
#pragma unroll
    for (int qb = 0; qb < 2; qb++)
#pragma unroll
      for (int r = 0; r < 4; r++) {
        mrow[qb][r] = -1e30f;
        lrow[qb][r] = 0.0f;
      }

#pragma unroll 1
    for (int kt = ktA; kt < ktB; ++kt) {
      const int k0 = kt * 32;
      f32x4 sacc[2][2] = {};
      __builtin_amdgcn_s_setprio(1);
#pragma unroll
      for (int kb = 0; kb < 2; kb++)
#pragma unroll
        for (int dc = 0; dc < 4; dc++) {
          const bf16x8 kf =
              *(const bf16x8*)&Kb[(long)(k0 + kb * 16 + lo) * 6144 + dc * 32 + hi * 8];
          sacc[0][kb] = MFMA16(qf[0][dc], kf, sacc[0][kb]);
          sacc[1][kb] = MFMA16(qf[1][dc], kf, sacc[1][kb]);
        }
      __builtin_amdgcn_s_setprio(0);

      if (kt == qw) {  // diagonal tile (only reachable in its owning half)
#pragma unroll
        for (int qb = 0; qb < 2; qb++)
#pragma unroll
          for (int kb = 0; kb < 2; kb++) {
            const int q = q0 + qb * 16 + hi * 4;
            const int k = k0 + kb * 16 + lo;
#pragma unroll
            for (int r = 0; r < 4; r++)
              if (k > q + r) sacc[qb][kb][r] = -1e30f;
          }
      }

      float p[2][2][4];
      float sf[2][4];
#pragma unroll
      for (int qb = 0; qb < 2; qb++)
#pragma unroll
        for (int r = 0; r < 4; r++) {
          float pm = fmaxf(sacc[qb][0][r], sacc[qb][1][r]);
          pm = fmaxf(pm, __shfl_xor(pm, 1));
          pm = fmaxf(pm, __shfl_xor(pm, 2));
          pm = fmaxf(pm, __shfl_xor(pm, 4));
          pm = fmaxf(pm, __shfl_xor(pm, 8));
          const float mn = fmaxf(mrow[qb][r], pm);
          sf[qb][r] = __expf(mrow[qb][r] - mn);
          mrow[qb][r] = mn;
          float ps = 0.0f;
#pragma unroll
          for (int kb = 0; kb < 2; kb++) {
            p[qb][kb][r] = __expf(sacc[qb][kb][r] - mn);
            ps += p[qb][kb][r];
          }
          ps += __shfl_xor(ps, 1);
          ps += __shfl_xor(ps, 2);
          ps += __shfl_xor(ps, 4);
          ps += __shfl_xor(ps, 8);
          lrow[qb][r] = lrow[qb][r] * sf[qb][r] + ps;
        }

#pragma unroll
      for (int qb = 0; qb < 2; qb++)
#pragma unroll
        for (int dt = 0; dt < 8; dt++)
#pragma unroll
          for (int r = 0; r < 4; r++) acc[qb][dt][r] *= sf[qb][r];

#pragma unroll
      for (int qb = 0; qb < 2; qb++)
#pragma unroll
        for (int kb = 0; kb < 2; kb++)
#pragma unroll
          for (int r = 0; r < 4; r++)
            Plds[wave][qb * 16 + hi * 4 + r][kb * 16 + lo] = __float2bfloat16(p[qb][kb][r]);

      bf16x8 pa[2];
#pragma unroll
      for (int qb = 0; qb < 2; qb++)
        pa[qb] = *(const bf16x8*)&Plds[wave][qb * 16 + lo][hi * 8];

      __builtin_amdgcn_s_setprio(1);
#pragma unroll
      for (int dt = 0; dt < 8; dt++) {
        const bf16x8 vf = *(const bf16x8*)&Vb[(long)(dt * 16 + lo) * 2048 + k0 + hi * 8];
        acc[0][dt] = MFMA16(pa[0], vf, acc[0][dt]);
        acc[1][dt] = MFMA16(pa[1], vf, acc[1][dt]);
      }
      __builtin_amdgcn_s_setprio(0);
    }

    // partial epilogue: raw acc (NOT divided by l), plus (m, l) per row
    const long rbase = ((long)(b * 32 + h)) * 2048 + q0;
#pragma unroll
    for (int qb = 0; qb < 2; qb++)
#pragma unroll
      for (int dt = 0; dt < 8; dt++)
#pragma unroll
        for (int r = 0; r < 4; r++) {
          const long row = rbase + qb * 16 + hi * 4 + r;
          Pacc[(hoff + row) * 128 + dt * 16 + lo] = __float2bfloat16(acc[qb][dt][r]);
        }
    if (lo == 0) {
#pragma unroll
      for (int qb = 0; qb < 2; qb++)
#pragma unroll
        for (int r = 0; r < 4; r++) {
          const long row = rbase + qb * 16 + hi * 4 + r;
          Pml[(hoff + row) * 2 + 0] = mrow[qb][r];
          Pml[(hoff + row) * 2 + 1] = lrow[qb][r];
        }
    }
  }
}

// ---------------------------------------------------------------------------
// Merge two KV-halves: out = (accA*e^(mA-m) + accB*e^(mB-m)) / l.
// 16 rows/block (16 threads x 8 cols each). grid 8192, block 256.
// ---------------------------------------------------------------------------
__global__ __launch_bounds__(256) void attn_merge(const bf16* __restrict__ Pacc,
                                                  const float* __restrict__ Pml,
                                                  bf16* __restrict__ Ctx) {
  const int tid = threadIdx.x;
  const long rid = (long)blockIdx.x * 16 + (tid >> 4);  // 0..131071
  const int col0 = (tid & 15) * 8;

  const float mA = Pml[rid * 2 + 0], lA = Pml[rid * 2 + 1];
  const float mB = Pml[(131072 + rid) * 2 + 0], lB = Pml[(131072 + rid) * 2 + 1];
  const float m = fmaxf(mA, mB);
  const float eA = __expf(mA - m), eB = __expf(mB - m);
  const float rl = 1.0f / (lA * eA + lB * eB);
  const float wA = eA * rl, wB = eB * rl;

  const bf16x8 a8 = *(const bf16x8*)&Pacc[rid * 128 + col0];
  const bf16x8 b8 = *(const bf16x8*)&Pacc[(131072 + rid) * 128 + col0];
  bf16 o[8];
#pragma unroll
  for (int j = 0; j < 8; j++) {
    const float av = __bfloat162float(((const bf16*)&a8)[j]);
    const float bv = __bfloat162float(((const bf16*)&b8)[j]);
    o[j] = __float2bfloat16(av * wA + bv * wB);
  }
  const long t = rid & 2047, bh = rid >> 11;
  const long brow = (bh >> 5) * 2048 + t;
  const long col = (bh & 31) * 128 + col0;
  *(bf16x8*)&Ctx[brow * 4096 + col] = *(const bf16x8*)o;
}

// ---------------------------------------------------------------------------
// Fallback attention (r9-verified, 300us): used if ws too small for partials.
// ---------------------------------------------------------------------------
__global__ __launch_bounds__(256) void attn_fused(const bf16* __restrict__ qkv,
                                                  const bf16* __restrict__ Vt,
                                                  bf16* __restrict__ Ctx) {
  const int lin = blockIdx.x;                 // 0..511
  const int c = (lin & 7) * 64 + (lin >> 3);  // XCD-contiguous chunks of 64
  const int z = c & 31;
  const int kvh = (c >> 5) & 7;
  const int b = c >> 8;

  const int wave = threadIdx.x >> 6;
  const int lane = threadIdx.x & 63;
  const int h = kvh * 4 + wave;
  const int lo = lane & 15, hi = lane >> 4;

  const bf16* Qb = qkv + (long)b * 2048 * 6144 + kvh * 768 + wave * 128;
  const bf16* Kb = qkv + (long)b * 2048 * 6144 + kvh * 768 + 512;
  const bf16* Vb = Vt + ((long)(b * 8 + kvh)) * 128 * 2048;

  __shared__ bf16 Plds[4][32][40];

#pragma unroll 1
  for (int pass = 0; pass < 2; ++pass) {
    const int qw = pass ? 63 - z : z;
    const int q0 = qw * 32;

    bf16x8 qf[2][4];
#pragma unroll
    for (int qb = 0; qb < 2; qb++)
#pragma unroll
      for (int dc = 0; dc < 4; dc++)
        qf[qb][dc] =
            *(const bf16x8*)&Qb[(long)(q0 + qb * 16 + lo) * 6144 + dc * 32 + hi * 8];

    f32x4 acc[2][8] = {};
    float mrow[2][4], lrow[2][4];
#pragma unroll
    for (int qb = 0; qb < 2; qb++)
#pragma unroll
      for (int r = 0; r < 4; r++) {
        mrow[qb][r] = -1e30f;
        lrow[qb][r] = 0.0f;
      }

    for (int kt = 0; kt <= qw; ++kt) {
      const int k0 = kt * 32;
      f32x4 sacc[2][2] = {};
      __builtin_amdgcn_s_setprio(1);
#pragma unroll
      for (int kb = 0; kb < 2; kb++)
#pragma unroll
        for (int dc = 0; dc < 4; dc++) {
          const bf16x8 kf =
              *(const bf16x8*)&Kb[(long)(k0 + kb * 16 + lo) * 6144 + dc * 32 + hi * 8];
          sacc[0][kb] = MFMA16(qf[0][dc], kf, sacc[0][kb]);
          sacc[1][kb] = MFMA16(qf[1][dc], kf, sacc[1][kb]);
        }
      __builtin_amdgcn_s_setprio(0);

      if (kt == qw) {
#pragma unroll
        for (int qb = 0; qb < 2; qb++)
#pragma unroll
          for (int kb = 0; kb < 2; kb++) {
            const int q = q0 + qb * 16 + hi * 4;
            const int k = k0 + kb * 16 + lo;
#pragma unroll
            for (int r = 0; r < 4; r++)
              if (k > q + r) sacc[qb][kb][r] = -1e30f;
          }
      }

      float p[2][2][4];
      float sf[2][4];
#pragma unroll
      for (int qb = 0; qb < 2; qb++)
#pragma unroll
        for (int r = 0; r < 4; r++) {
          float pm = fmaxf(sacc[qb][0][r], sacc[qb][1][r]);
          pm = fmaxf(pm, __shfl_xor(pm, 1));
          pm = fmaxf(pm, __shfl_xor(pm, 2));
          pm = fmaxf(pm, __shfl_xor(pm, 4));
          pm = fmaxf(pm, __shfl_xor(pm, 8));
          const float mn = fmaxf(mrow[qb][r], pm);
          sf[qb][r] = __expf(mrow[qb][r] - mn);
          mrow[qb][r] = mn;
          float ps = 0.0f;
#pragma unroll
          for (int kb = 0; kb < 2; kb++) {
            p[qb][kb][r] = __expf(sacc[qb][kb][r] - mn);
            ps += p[qb][kb][r];
          }
          ps += __shfl_xor(ps, 1);
          ps += __shfl_xor(ps, 2);
          ps += __shfl_xor(ps, 4);
          ps += __shfl_xor(ps, 8);
          lrow[qb][r] = lrow[qb][r] * sf[qb][r] + ps;
        }

#pragma unroll
      for (int qb = 0; qb < 2; qb++)
#pragma unroll
        for (int dt = 0; dt < 8; dt++)
#pragma unroll
          for (int r = 0; r < 4; r++) acc[qb][dt][r] *= sf[qb][r];

#pragma unroll
      for (int qb = 0; qb < 2; qb++)
#pragma unroll
        for (int kb = 0; kb < 2; kb++)
#pragma unroll
          for (int r = 0; r < 4; r++)
            Plds[wave][qb * 16 + hi * 4 + r][kb * 16 + lo] = __float2bfloat16(p[qb][kb][r]);

      bf16x8 pa[2];
#pragma unroll
      for (int qb = 0; qb < 2; qb++)
        pa[qb] = *(const bf16x8*)&Plds[wave][qb * 16 + lo][hi * 8];

      __builtin_amdgcn_s_setprio(1);
#pragma unroll
      for (int dt = 0; dt < 8; dt++) {
        const bf16x8 vf = *(const bf16x8*)&Vb[(long)(dt * 16 + lo) * 2048 + k0 + hi * 8];
        acc[0][dt] = MFMA16(pa[0], vf, acc[0][dt]);
        acc[1][dt] = MFMA16(pa[1], vf, acc[1][dt]);
      }
      __builtin_amdgcn_s_setprio(0);
    }

#pragma unroll
    for (int qb = 0; qb < 2; qb++)
#pragma unroll
      for (int dt = 0; dt < 8; dt++)
#pragma unroll
        for (int r = 0; r < 4; r++) {
          const float o = acc[qb][dt][r] / lrow[qb][r];
          const long row = (long)b * 2048 + q0 + qb * 16 + hi * 4 + r;
          Ctx[row * 4096 + h * 128 + dt * 16 + lo] = __float2bfloat16(o);
        }
  }
}

// ---------------------------------------------------------------------------

extern "C" void kernel_launch(void* const* d_in, const int* in_sizes, int n_in,
                              void* d_out, int out_size, void* d_ws, size_t ws_size,
                              hipStream_t stream) {
  (void)in_sizes; (void)n_in; (void)out_size;
  const float* x = (const float*)d_in[0];      // [2,2048,4096] fp32
  const float* wqkv = (const float*)d_in[1];   // [6144,4096] fp32
  const float* wo = (const float*)d_in[2];     // [4096,4096] fp32
  float* out = (float*)d_out;                  // [2,2048,4096] fp32

  const long NX = 4096L * 4096;
  const long NW1 = 6144L * 4096;

  const size_t XB_B = (size_t)NX * 2;      // 33.6 MB
  const size_t WQ_B = (size_t)NW1 * 2;     // 50.3 MB
  const size_t QKV_B = WQ_B;               // 50.3 MB
  const size_t VT_B = 2ULL * 8 * 128 * 2048 * 2;  // 8.4... (b=2,kvh=8): 16.8 MB
  const size_t PACC_B = 262144ULL * 128 * 2;      // 67.1 MB
  const size_t NEEDED = XB_B + WQ_B + QKV_B + VT_B + PACC_B + 262144ULL * 2 * 4;

  char* w = (char*)d_ws;
  bf16* xb = (bf16*)w;                 // later: wob
  bf16* wqkvb = (bf16*)(w + XB_B);     // later: ctx
  bf16* qkvp = (bf16*)(w + XB_B + WQ_B);
  bf16* Vtp = (bf16*)(w + XB_B + WQ_B + QKV_B);
  bf16* Paccp = (bf16*)(w + XB_B + WQ_B + QKV_B + VT_B);
  float* Pmlp = (float*)(w + XB_B + WQ_B + QKV_B + VT_B + PACC_B);
  bf16* wob = xb;
  bf16* ctx = wqkvb;

  // 1. casts for GEMM1
  cast_f32_bf16<<<2048, 256, 0, stream>>>(x, xb, NX);
  cast_f32_bf16<<<2048, 256, 0, stream>>>(wqkv, wqkvb, NW1);

  // 2. QKV projection: qkv[4096,6144] = xb @ wqkvb^T   (16x24 = 384 tiles)
  gemm256<bf16><<<16 * 24, 512, 0, stream>>>(xb, wqkvb, qkvp, 4096, 6144, 4096);

  // 3. RoPE in-place (Q scaled), V transpose
  rope_qk<<<4096, 256, 0, stream>>>(qkvp);
  vtrans<<<dim3(32, 2, 16), dim3(64, 4), 0, stream>>>(qkvp, Vtp);

  // 4. cast wo into xb's space (xb dead after GEMM1)
  cast_f32_bf16<<<2048, 256, 0, stream>>>(wo, wob, NX);

  // 5. attention -> ctx (wqkvb's space, dead after GEMM1)
  if (ws_size >= NEEDED) {
    attn_split<<<dim3(1024), 256, 0, stream>>>(qkvp, Vtp, Paccp, Pmlp);
    attn_merge<<<dim3(8192), 256, 0, stream>>>(Paccp, Pmlp, ctx);
  } else {
    attn_fused<<<dim3(512), 256, 0, stream>>>(qkvp, Vtp, ctx);
  }

  // 6. output projection: out(fp32) = ctx @ wob^T   (16x16 = 256 tiles)
  gemm256<float><<<16 * 16, 512, 0, stream>>>(ctx, wob, out, 4096, 4096, 4096);
}

// Round 12
// 728.538 us; speedup vs baseline: 1.3041x; 1.3041x over previous
//
#include <hip/hip_runtime.h>
#include <hip/hip_bf16.h>
#include <stdint.h>

typedef __hip_bfloat16 bf16;
typedef short bf16x8 __attribute__((ext_vector_type(8)));
typedef float f32x4 __attribute__((ext_vector_type(4)));

#define MFMA16(a, b, c) __builtin_amdgcn_mfma_f32_16x16x32_bf16((a), (b), (c), 0, 0, 0)

__device__ __forceinline__ void gload16(const void* g, void* l) {
  __builtin_amdgcn_global_load_lds((const __attribute__((address_space(1))) void*)g,
                                   (__attribute__((address_space(3))) void*)l,
                                   16, 0, 0);
}

__device__ __forceinline__ void stv(float* p, float v) { *p = v; }
__device__ __forceinline__ void stv(bf16* p, float v) { *p = __float2bfloat16(v); }

// ---------------------------------------------------------------------------
// fp32 -> bf16 cast (vectorized, grid-stride). n % 8 == 0.
// ---------------------------------------------------------------------------
__global__ void cast_f32_bf16(const float* __restrict__ in, bf16* __restrict__ out,
                              long n) {
  const long stride = (long)gridDim.x * blockDim.x * 8;
  for (long i = ((long)blockIdx.x * blockDim.x + threadIdx.x) * 8; i < n; i += stride) {
    const float4 a = *(const float4*)&in[i];
    const float4 b = *(const float4*)&in[i + 4];
    bf16 t[8];
    t[0] = __float2bfloat16(a.x); t[1] = __float2bfloat16(a.y);
    t[2] = __float2bfloat16(a.z); t[3] = __float2bfloat16(a.w);
    t[4] = __float2bfloat16(b.x); t[5] = __float2bfloat16(b.y);
    t[6] = __float2bfloat16(b.z); t[7] = __float2bfloat16(b.w);
    *(bf16x8*)&out[i] = *(const bf16x8*)t;
  }
}

// ---------------------------------------------------------------------------
// GEMM round-12: C[M,N] = A[M,K] * B[N,K]^T  (bf16 in, fp32 accum, OutT out)
// 256x256 tile, BK=64, 8 waves (2M x 4N), 2-buffer LDS (128 KB), 2 barriers
// per tile (64 MFMA : 2 barriers). Staging for tile t+2 issued at END of
// tile t (after all reads of that buffer retired chip-wide -> race-free).
// Counted vmcnt(8) at tile top; vmcnt(0) only on the last tile.
// XOR swizzle: physical chunk p = logical ^ (row&7), via pre-swizzled global
// source (linear gload_lds dest) + swizzled ds_read -> b128 bank floor.
// Requires M%256==0, N%256==0, K%64==0, NT>=2, grid%8==0.
// ---------------------------------------------------------------------------
template <typename OutT>
__global__ __launch_bounds__(512, 2) void gemm256(const bf16* __restrict__ A,
                                                  const bf16* __restrict__ B,
                                                  OutT* __restrict__ C,
                                                  int M, int N, int K) {
  const int nbn = N >> 8;
  const int nwg = gridDim.x;
  const int wg = blockIdx.x;
  const int cpx = nwg >> 3;                    // nwg % 8 == 0 guaranteed
  const int swz = (wg & 7) * cpx + (wg >> 3);  // XCD-aware swizzle (bijective)
  const int bm = swz / nbn;
  const int bn = swz - bm * nbn;

  __shared__ bf16 As[2][256][64];  // 64 KB
  __shared__ bf16 Bs[2][256][64];  // 64 KB

  const int tid = threadIdx.x;
  const int wave = tid >> 6, lane = tid & 63;
  const int lo = lane & 15, hi = lane >> 4;
  const int wm = wave >> 2, wn = wave & 3;

  const bf16* Ag = A + (long)(bm * 256) * K;
  const bf16* Bg = B + (long)(bn * 256) * K;

  // staging constants: chunk c = i*512 + wave*64 + lane (i=0..3);
  // row = c>>3, physical chunk p = c&7, logical (global) chunk l = p^(row&7)
  int srow[4]; int scol[4]; int sdst[4];
#pragma unroll
  for (int i = 0; i < 4; i++) {
    const int c = i * 512 + wave * 64 + lane;
    const int row = c >> 3, p = c & 7;
    srow[i] = row;
    scol[i] = (p ^ (row & 7)) * 8;          // global col offset (elements)
    sdst[i] = (i * 512 + wave * 64) * 8;    // wave-uniform LDS base (elements)
  }

  f32x4 acc[8][4] = {};
  const int NT = K >> 6;

  // prologue: stage tiles 0 and 1 (A then B per tile; 8 loads/thread/tile)
#pragma unroll
  for (int p = 0; p < 2; p++) {
#pragma unroll
    for (int i = 0; i < 4; i++)
      gload16(Ag + (long)srow[i] * K + p * 64 + scol[i], &As[p][0][0] + sdst[i]);
#pragma unroll
    for (int i = 0; i < 4; i++)
      gload16(Bg + (long)srow[i] * K + p * 64 + scol[i], &Bs[p][0][0] + sdst[i]);
  }

#pragma unroll 1
  for (int t = 0; t < NT; ++t) {
    if (t >= NT - 1) asm volatile("s_waitcnt vmcnt(0)" ::: "memory");
    else             asm volatile("s_waitcnt vmcnt(8)" ::: "memory");
    __builtin_amdgcn_s_barrier();

    const bf16* Ab = &As[t & 1][0][0];
    const bf16* Bb = &Bs[t & 1][0][0];

    // compute: 2 k-halves x (8m x 4n) MFMA; reads swizzle-matched
#pragma unroll
    for (int ks = 0; ks < 2; ks++) {
      bf16x8 af[8], bfr[4];
#pragma unroll
      for (int m = 0; m < 8; m++) {
        const int row = wm * 128 + m * 16 + lo;
        af[m] = *(const bf16x8*)&Ab[row * 64 + ((ks * 4 + hi) ^ (lo & 7)) * 8];
      }
#pragma unroll
      for (int n = 0; n < 4; n++) {
        const int row = wn * 64 + n * 16 + lo;
        bfr[n] = *(const bf16x8*)&Bb[row * 64 + ((ks * 4 + hi) ^ (lo & 7)) * 8];
      }
      __builtin_amdgcn_s_setprio(1);
#pragma unroll
      for (int m = 0; m < 8; m++)
#pragma unroll
        for (int n = 0; n < 4; n++) acc[m][n] = MFMA16(af[m], bfr[n], acc[m][n]);
      __builtin_amdgcn_s_setprio(0);
    }

    // all reads of buf[t&1] retired chip-wide after this barrier
    asm volatile("s_waitcnt lgkmcnt(0)" ::: "memory");
    __builtin_amdgcn_s_barrier();

    if (t + 2 < NT) {  // stage tile t+2 into buf[t&1] (safe: reads done)
      const int kt = (t + 2) * 64;
      bf16* Ad = &As[t & 1][0][0];
      bf16* Bd = &Bs[t & 1][0][0];
#pragma unroll
      for (int i = 0; i < 4; i++)
        gload16(Ag + (long)srow[i] * K + kt + scol[i], Ad + sdst[i]);
#pragma unroll
      for (int i = 0; i < 4; i++)
        gload16(Bg + (long)srow[i] * K + kt + scol[i], Bd + sdst[i]);
    }
  }

  const long crow0 = (long)bm * 256 + wm * 128;
  const long ccol0 = (long)bn * 256 + wn * 64;
#pragma unroll
  for (int m = 0; m < 8; m++)
#pragma unroll
    for (int n = 0; n < 4; n++)
#pragma unroll
      for (int r = 0; r < 4; r++)
        stv(&C[(crow0 + m * 16 + hi * 4 + r) * (long)N + ccol0 + n * 16 + lo],
            acc[m][n][r]);
}

// ---------------------------------------------------------------------------
// RoPE in-place on qkv[4096][6144]; Q slots also scaled by 1/sqrt(128).
// ---------------------------------------------------------------------------
__global__ void rope_qk(bf16* __restrict__ qkv) {
  const int row = blockIdx.x;
  const int t = row & 2047;
  const float scale = 0.08838834764831845f;  // 128^-0.5
  for (int p = threadIdx.x; p < 40 * 64; p += blockDim.x) {
    const int sh = p >> 6, j = p & 63;
    const int kvh = sh / 5, slot = sh - kvh * 5;
    const long base = (long)row * 6144 + kvh * 768 + slot * 128 + j;
    const float x1 = __bfloat162float(qkv[base]);
    const float x2 = __bfloat162float(qkv[base + 64]);
    const float inv = __expf(-(float)j * 0.14391156831212787f);  // ln(1e4)/64
    const float ang = (float)t * inv;
    const float c = cosf(ang), s = sinf(ang);
    float o1 = x1 * c - x2 * s;
    float o2 = x2 * c + x1 * s;
    if (slot < 4) { o1 *= scale; o2 *= scale; }
    qkv[base] = __float2bfloat16(o1);
    qkv[base + 64] = __float2bfloat16(o2);
  }
}

// ---------------------------------------------------------------------------
// V transpose: qkv V-slice [t][d] -> Vt[b][kvh][d][t]  (64x64 tiles via LDS)
// ---------------------------------------------------------------------------
__global__ void vtrans(const bf16* __restrict__ qkv, bf16* __restrict__ Vt) {
  const int tt = blockIdx.x, dd = blockIdx.y, bk = blockIdx.z;
  const int kvh = bk & 7, b = bk >> 3;
  __shared__ bf16 tile[64][65];
  const int tx = threadIdx.x, ty = threadIdx.y;
  const bf16* src = qkv + ((long)(b * 2048 + tt * 64)) * 6144 + kvh * 768 + 640 + dd * 64;
  for (int r = ty; r < 64; r += 4) tile[r][tx] = src[(long)r * 6144 + tx];
  __syncthreads();
  bf16* dst = Vt + ((long)bk * 128 + dd * 64) * 2048 + tt * 64;
  for (int r = ty; r < 64; r += 4) dst[(long)r * 2048 + tx] = tile[tx][r];
}

// ---------------------------------------------------------------------------
// Causal GQA flash attention (r9-verified, 300us). 4 waves/block share one
// kvh; wave w = q-head kvh*4+w; two balanced passes (qw = z, 63-z). No
// barriers. XCD remap: one (kvh,b) per XCD -> K/V L2-resident.
// grid 512, block 256.
// ---------------------------------------------------------------------------
__global__ __launch_bounds__(256) void attn(const bf16* __restrict__ qkv,
                                            const bf16* __restrict__ Vt,
                                            bf16* __restrict__ Ctx) {
  const int lin = blockIdx.x;                 // 0..511
  const int c = (lin & 7) * 64 + (lin >> 3);  // XCD-contiguous chunks of 64
  const int z = c & 31;
  const int kvh = (c >> 5) & 7;
  const int b = c >> 8;

  const int wave = threadIdx.x >> 6;
  const int lane = threadIdx.x & 63;
  const int h = kvh * 4 + wave;
  const int lo = lane & 15, hi = lane >> 4;

  const bf16* Qb = qkv + (long)b * 2048 * 6144 + kvh * 768 + wave * 128;
  const bf16* Kb = qkv + (long)b * 2048 * 6144 + kvh * 768 + 512;
  const bf16* Vb = Vt + ((long)(b * 8 + kvh)) * 128 * 2048;

  __shared__ bf16 Plds[4][32][40];  // per-wave, padded rows

#pragma unroll 1
  for (int pass = 0; pass < 2; ++pass) {
    const int qw = pass ? 63 - z : z;
    const int q0 = qw * 32;

    bf16x8 qf[2][4];
#pragma unroll
    for (int qb = 0; qb < 2; qb++)
#pragma unroll
      for (int dc = 0; dc < 4; dc++)
        qf[qb][dc] =
            *(const bf16x8*)&Qb[(long)(q0 + qb * 16 + lo) * 6144 + dc * 32 + hi * 8];

    f32x4 acc[2][8] = {};
    float mrow[2][4], lrow[2][4];
#pragma unroll
    for (int qb = 0; qb < 2; qb++)
#pragma unroll
      for (int r = 0; r < 4; r++) {
        mrow[qb][r] = -1e30f;
        lrow[qb][r] = 0.0f;
      }

    for (int kt = 0; kt <= qw; ++kt) {
      const int k0 = kt * 32;
      f32x4 sacc[2][2] = {};
      __builtin_amdgcn_s_setprio(1);
#pragma unroll
      for (int kb = 0; kb < 2; kb++)
#pragma unroll
        for (int dc = 0; dc < 4; dc++) {
          const bf16x8 kf =
              *(const bf16x8*)&Kb[(long)(k0 + kb * 16 + lo) * 6144 + dc * 32 + hi * 8];
          sacc[0][kb] = MFMA16(qf[0][dc], kf, sacc[0][kb]);
          sacc[1][kb] = MFMA16(qf[1][dc], kf, sacc[1][kb]);
        }
      __builtin_amdgcn_s_setprio(0);

      if (kt == qw) {  // diagonal tile: causal mask (D row q = hi*4+r, col k = lo)
#pragma unroll
        for (int qb = 0; qb < 2; qb++)
#pragma unroll
          for (int kb = 0; kb < 2; kb++) {
            const int q = q0 + qb * 16 + hi * 4;
            const int k = k0 + kb * 16 + lo;
#pragma unroll
            for (int r = 0; r < 4; r++)
              if (k > q + r) sacc[qb][kb][r] = -1e30f;
          }
      }

      float p[2][2][4];
      float sf[2][4];
#pragma unroll
      for (int qb = 0; qb < 2; qb++)
#pragma unroll
        for (int r = 0; r < 4; r++) {
          float pm = fmaxf(sacc[qb][0][r], sacc[qb][1][r]);
          pm = fmaxf(pm, __shfl_xor(pm, 1));
          pm = fmaxf(pm, __shfl_xor(pm, 2));
          pm = fmaxf(pm, __shfl_xor(pm, 4));
          pm = fmaxf(pm, __shfl_xor(pm, 8));
          const float mn = fmaxf(mrow[qb][r], pm);
          sf[qb][r] = __expf(mrow[qb][r] - mn);
          mrow[qb][r] = mn;
          float ps = 0.0f;
#pragma unroll
          for (int kb = 0; kb < 2; kb++) {
            p[qb][kb][r] = __expf(sacc[qb][kb][r] - mn);
            ps += p[qb][kb][r];
          }
          ps += __shfl_xor(ps, 1);
          ps += __shfl_xor(ps, 2);
          ps += __shfl_xor(ps, 4);
          ps += __shfl_xor(ps, 8);
          lrow[qb][r] = lrow[qb][r] * sf[qb][r] + ps;
        }

#pragma unroll
      for (int qb = 0; qb < 2; qb++)
#pragma unroll
        for (int dt = 0; dt < 8; dt++)
#pragma unroll
          for (int r = 0; r < 4; r++) acc[qb][dt][r] *= sf[qb][r];

#pragma unroll
      for (int qb = 0; qb < 2; qb++)
#pragma unroll
        for (int kb = 0; kb < 2; kb++)
#pragma unroll
          for (int r = 0; r < 4; r++)
            Plds[wave][qb * 16 + hi * 4 + r][kb * 16 + lo] = __float2bfloat16(p[qb][kb][r]);

      bf16x8 pa[2];
#pragma unroll
      for (int qb = 0; qb < 2; qb++)
        pa[qb] = *(const bf16x8*)&Plds[wave][qb * 16 + lo][hi * 8];

      __builtin_amdgcn_s_setprio(1);
#pragma unroll
      for (int dt = 0; dt < 8; dt++) {
        const bf16x8 vf = *(const bf16x8*)&Vb[(long)(dt * 16 + lo) * 2048 + k0 + hi * 8];
        acc[0][dt] = MFMA16(pa[0], vf, acc[0][dt]);
        acc[1][dt] = MFMA16(pa[1], vf, acc[1][dt]);
      }
      __builtin_amdgcn_s_setprio(0);
    }

#pragma unroll
    for (int qb = 0; qb < 2; qb++)
#pragma unroll
      for (int dt = 0; dt < 8; dt++)
#pragma unroll
        for (int r = 0; r < 4; r++) {
          const float o = acc[qb][dt][r] / lrow[qb][r];
          const long row = (long)b * 2048 + q0 + qb * 16 + hi * 4 + r;
          Ctx[row * 4096 + h * 128 + dt * 16 + lo] = __float2bfloat16(o);
        }
  }
}

// ---------------------------------------------------------------------------

extern "C" void kernel_launch(void* const* d_in, const int* in_sizes, int n_in,
                              void* d_out, int out_size, void* d_ws, size_t ws_size,
                              hipStream_t stream) {
  (void)in_sizes; (void)n_in; (void)out_size; (void)ws_size;
  const float* x = (const float*)d_in[0];      // [2,2048,4096] fp32
  const float* wqkv = (const float*)d_in[1];   // [6144,4096] fp32
  const float* wo = (const float*)d_in[2];     // [4096,4096] fp32
  float* out = (float*)d_out;                  // [2,2048,4096] fp32

  const long NX = 4096L * 4096;
  const long NW1 = 6144L * 4096;

  const size_t XB_B = (size_t)NX * 2;
  const size_t WQ_B = (size_t)NW1 * 2;
  const size_t QKV_B = WQ_B;

  char* w = (char*)d_ws;
  bf16* xb = (bf16*)w;                 // later: wob
  bf16* wqkvb = (bf16*)(w + XB_B);     // later: ctx
  bf16* qkvp = (bf16*)(w + XB_B + WQ_B);
  bf16* Vtp = (bf16*)(w + XB_B + WQ_B + QKV_B);
  bf16* wob = xb;
  bf16* ctx = wqkvb;

  // 1. casts for GEMM1
  cast_f32_bf16<<<2048, 256, 0, stream>>>(x, xb, NX);
  cast_f32_bf16<<<2048, 256, 0, stream>>>(wqkv, wqkvb, NW1);

  // 2. QKV projection: qkv[4096,6144] = xb @ wqkvb^T   (16x24 = 384 tiles)
  gemm256<bf16><<<16 * 24, 512, 0, stream>>>(xb, wqkvb, qkvp, 4096, 6144, 4096);

  // 3. RoPE in-place (Q scaled), V transpose
  rope_qk<<<4096, 256, 0, stream>>>(qkvp);
  vtrans<<<dim3(32, 2, 16), dim3(64, 4), 0, stream>>>(qkvp, Vtp);

  // 4. cast wo into xb's space (xb dead after GEMM1)
  cast_f32_bf16<<<2048, 256, 0, stream>>>(wo, wob, NX);

  // 5. attention -> ctx (wqkvb's space, dead after GEMM1)
  attn<<<dim3(512), 256, 0, stream>>>(qkvp, Vtp, ctx);

  // 6. output projection: out(fp32) = ctx @ wob^T   (16x16 = 256 tiles)
  gemm256<float><<<16 * 16, 512, 0, stream>>>(ctx, wob, out, 4096, 4096, 4096);
}